// Round 1
// baseline (1030.046 us; speedup 1.0000x reference)
//
#include <hip/hip_runtime.h>

#define DI __device__ __forceinline__

typedef short bfrag8 __attribute__((ext_vector_type(8)));
typedef float ffrag4 __attribute__((ext_vector_type(4)));

DI ushort f2b(float f){
  union { float f; unsigned u; } v; v.f = f;
  unsigned u = v.u;
  u += 0x7FFF + ((u >> 16) & 1);   // round-to-nearest-even
  return (ushort)(u >> 16);
}
DI float b2f(ushort h){
  union { unsigned u; float f; } v; v.u = ((unsigned)h) << 16;
  return v.f;
}
DI float sigm(float x){ return 1.0f / (1.0f + __expf(-x)); }
DI float tanh_(float x){ return 1.0f - 2.0f / (1.0f + __expf(2.0f * x)); }
DI float elu_(float x){ return x > 0.f ? x : __expf(x) - 1.f; }

// ---------------------------------------------------------------------------
// Tiny kernel: compute attention probs for a pair of GAT layers from sample 0.
// Launch: 1 block x 576 threads.
// ---------------------------------------------------------------------------
__global__ void k_probs(const float* xf, const ushort* xb, int in_c,
                        const float* W1, const float* b1, const float* a1, int hc1, int c1,
                        const float* W2, const float* b2, const float* a2, int hc2, int c2,
                        float* outA, float* outB)
{
  __shared__ float xs[12 * 22];
  __shared__ float h1[12 * 16];
  __shared__ float lg[4 * 144];
  __shared__ float pr[4 * 144];
  __shared__ float h1e[12 * 16];
  __shared__ float h2[12 * 24];
  const int t = threadIdx.x;
  const unsigned adj[12] = {0xC21u,0x482u,0x844u,0x048u,0x030u,0x031u,
                            0x44Cu,0x282u,0xF00u,0x780u,0xF43u,0xD05u};
  if (t < 12 * in_c){
    if (xf) xs[t] = xf[t];
    else    xs[t] = b2f(xb[t]);
  }
  __syncthreads();
  if (t < 12 * hc1){
    int i = t / hc1, o = t % hc1;
    float v = b1[o];
    for (int k = 0; k < in_c; k++) v += xs[i * in_c + k] * W1[k * hc1 + o];
    h1[t] = v;
  }
  __syncthreads();
  // logits layer A
  {
    int h = t / 144, ij = t % 144, i = ij / 12, j = ij % 12;
    float v;
    if ((adj[i] >> j) & 1){
      v = 0.f;
      for (int c = 0; c < c1; c++)
        v += a1[h*2*c1 + c] * h1[i*hc1 + h*c1 + c] + a1[h*2*c1 + c1 + c] * h1[j*hc1 + h*c1 + c];
      v = v > 0.f ? v : 0.2f * v;
    } else v = -9e15f;
    lg[t] = v;
  }
  __syncthreads();
  if (t < 48){
    int h = t / 12, i = t % 12;
    const float* row = &lg[h*144 + i*12];
    float m = row[0];
    for (int j = 1; j < 12; j++) m = fmaxf(m, row[j]);
    float e[12], s = 0.f;
    for (int j = 0; j < 12; j++){ e[j] = __expf(row[j] - m); s += e[j]; }
    float inv = 1.f / s;
    for (int j = 0; j < 12; j++){
      float p = e[j] * inv;
      pr[h*144 + i*12 + j] = p;
      outA[h*144 + i*12 + j] = p;
    }
  }
  __syncthreads();
  if (t < 12 * hc1){
    int i = t / hc1, o = t % hc1, h = o / c1;
    float v = 0.f;
    for (int j = 0; j < 12; j++) v += pr[h*144 + i*12 + j] * h1[j*hc1 + o];
    h1e[t] = elu_(v);
  }
  __syncthreads();
  if (t < 12 * hc2){
    int i = t / hc2, o = t % hc2;
    float v = b2[o];
    for (int k = 0; k < hc1; k++) v += h1e[i*hc1 + k] * W2[k*hc2 + o];
    h2[t] = v;
  }
  __syncthreads();
  {
    int h = t / 144, ij = t % 144, i = ij / 12, j = ij % 12;
    float v;
    if ((adj[i] >> j) & 1){
      v = 0.f;
      for (int c = 0; c < c2; c++)
        v += a2[h*2*c2 + c] * h2[i*hc2 + h*c2 + c] + a2[h*2*c2 + c2 + c] * h2[j*hc2 + h*c2 + c];
      v = v > 0.f ? v : 0.2f * v;
    } else v = -9e15f;
    lg[t] = v;
  }
  __syncthreads();
  if (t < 48){
    int h = t / 12, i = t % 12;
    const float* row = &lg[h*144 + i*12];
    float m = row[0];
    for (int j = 1; j < 12; j++) m = fmaxf(m, row[j]);
    float e[12], s = 0.f;
    for (int j = 0; j < 12; j++){ e[j] = __expf(row[j] - m); s += e[j]; }
    float inv = 1.f / s;
    for (int j = 0; j < 12; j++) outB[h*144 + i*12 + j] = e[j] * inv;
  }
}

// ---------------------------------------------------------------------------
// GAT layers 0+1 over the whole batch (attention probs precomputed).
// 16 samples per 256-thread block. Writes seq bf16 [98304][144].
// ---------------------------------------------------------------------------
__global__ __launch_bounds__(256) void k_gat01(
    const float* __restrict__ x, const float* __restrict__ W0, const float* __restrict__ b0,
    const float* __restrict__ W1, const float* __restrict__ b1,
    const float* __restrict__ p0g, const float* __restrict__ p1g,
    ushort* __restrict__ seq)
{
  __shared__ float xs[16 * 264];
  __shared__ float h1[16 * 192];
  __shared__ float h1e[16 * 192];
  __shared__ float h2[16 * 144];
  __shared__ float h2e[16 * 144];
  __shared__ float p0[576], p1[576];
  __shared__ float w0[352], bb0[16], w1[192], bb1[12];
  int t = threadIdx.x;
  long s0 = (long)blockIdx.x * 16;
  for (int i = t; i < 576; i += 256){ p0[i] = p0g[i]; p1[i] = p1g[i]; }
  for (int i = t; i < 352; i += 256) w0[i] = W0[i];
  if (t < 16) bb0[t] = b0[t];
  for (int i = t; i < 192; i += 256) w1[i] = W1[i];
  if (t < 12) bb1[t] = b1[t];
  for (int i = t; i < 16 * 264; i += 256) xs[i] = x[s0 * 264 + i];
  __syncthreads();
  // h1 = x@W0+b0 : thread (s, o16)
  {
    int o = t & 15, s = t >> 4;
    float wc[22];
    #pragma unroll
    for (int k = 0; k < 22; k++) wc[k] = w0[k*16 + o];
    for (int i = 0; i < 12; i++){
      float v = bb0[o];
      const float* xr = &xs[s*264 + i*22];
      #pragma unroll
      for (int k = 0; k < 22; k++) v += xr[k] * wc[k];
      h1[s*192 + i*16 + o] = v;
    }
  }
  __syncthreads();
  // attn0 + elu : thread (s, o16)
  {
    int s = t >> 4, o = t & 15, h = o >> 2;
    float hv[12];
    #pragma unroll
    for (int j = 0; j < 12; j++) hv[j] = h1[s*192 + j*16 + o];
    for (int i = 0; i < 12; i++){
      float v = 0.f;
      #pragma unroll
      for (int j = 0; j < 12; j++) v += p0[h*144 + i*12 + j] * hv[j];
      h1e[s*192 + i*16 + o] = elu_(v);
    }
  }
  __syncthreads();
  // h2 = h1e@W1+b1 : thread (s, o12), 192 active
  if (t < 192){
    int o = t % 12, s = t / 12;
    float wc[16];
    #pragma unroll
    for (int k = 0; k < 16; k++) wc[k] = w1[k*12 + o];
    for (int i = 0; i < 12; i++){
      float v = bb1[o];
      const float* hr = &h1e[s*192 + i*16];
      #pragma unroll
      for (int k = 0; k < 16; k++) v += hr[k] * wc[k];
      h2[s*144 + i*12 + o] = v;
    }
  }
  __syncthreads();
  // attn1 + elu : thread (s, o12), 192 active
  if (t < 192){
    int s = t / 12, o = t % 12, h = o / 3;
    float hv[12];
    #pragma unroll
    for (int j = 0; j < 12; j++) hv[j] = h2[s*144 + j*12 + o];
    for (int i = 0; i < 12; i++){
      float v = 0.f;
      #pragma unroll
      for (int j = 0; j < 12; j++) v += p1[h*144 + i*12 + j] * hv[j];
      h2e[s*144 + i*12 + o] = elu_(v);
    }
  }
  __syncthreads();
  for (int i = t; i < 2304; i += 256) seq[s0 * 144 + i] = f2b(h2e[i]);
}

// ---------------------------------------------------------------------------
// GAT layers 3+4 over the whole batch. Reads y bf16 [98304][144],
// writes G34 bf16 [98304][288].
// ---------------------------------------------------------------------------
__global__ __launch_bounds__(256) void k_gat34(
    const ushort* __restrict__ y, const float* __restrict__ W3, const float* __restrict__ b3,
    const float* __restrict__ W4, const float* __restrict__ b4,
    const float* __restrict__ p3g, const float* __restrict__ p4g,
    ushort* __restrict__ g34)
{
  __shared__ float xs[16 * 144];
  __shared__ float h3[16 * 192];
  __shared__ float h3e[16 * 192];
  __shared__ float h4[16 * 288];
  __shared__ float h4e[16 * 288];
  __shared__ float p3[576], p4[576];
  __shared__ float w3[192], bb3[16], w4[384], bb4[24];
  int t = threadIdx.x;
  long s0 = (long)blockIdx.x * 16;
  for (int i = t; i < 576; i += 256){ p3[i] = p3g[i]; p4[i] = p4g[i]; }
  for (int i = t; i < 192; i += 256) w3[i] = W3[i];
  if (t < 16) bb3[t] = b3[t];
  for (int i = t; i < 384; i += 256) w4[i] = W4[i];
  if (t < 24) bb4[t] = b4[t];
  for (int i = t; i < 2304; i += 256) xs[i] = b2f(y[s0 * 144 + i]);
  __syncthreads();
  // h3 = y@W3+b3 : thread (s, o16)
  {
    int o = t & 15, s = t >> 4;
    float wc[12];
    #pragma unroll
    for (int k = 0; k < 12; k++) wc[k] = w3[k*16 + o];
    for (int i = 0; i < 12; i++){
      float v = bb3[o];
      const float* xr = &xs[s*144 + i*12];
      #pragma unroll
      for (int k = 0; k < 12; k++) v += xr[k] * wc[k];
      h3[s*192 + i*16 + o] = v;
    }
  }
  __syncthreads();
  {
    int s = t >> 4, o = t & 15, h = o >> 2;
    float hv[12];
    #pragma unroll
    for (int j = 0; j < 12; j++) hv[j] = h3[s*192 + j*16 + o];
    for (int i = 0; i < 12; i++){
      float v = 0.f;
      #pragma unroll
      for (int j = 0; j < 12; j++) v += p3[h*144 + i*12 + j] * hv[j];
      h3e[s*192 + i*16 + o] = elu_(v);
    }
  }
  __syncthreads();
  // h4 = h3e@W4+b4 : (s, o24) = 384 tasks
  for (int idx = t; idx < 384; idx += 256){
    int o = idx % 24, s = idx / 24;
    float wc[16];
    #pragma unroll
    for (int k = 0; k < 16; k++) wc[k] = w4[k*24 + o];
    for (int i = 0; i < 12; i++){
      float v = bb4[o];
      const float* hr = &h3e[s*192 + i*16];
      #pragma unroll
      for (int k = 0; k < 16; k++) v += hr[k] * wc[k];
      h4[s*288 + i*24 + o] = v;
    }
  }
  __syncthreads();
  for (int idx = t; idx < 384; idx += 256){
    int s = idx / 24, o = idx % 24, h = o / 6;
    float hv[12];
    #pragma unroll
    for (int j = 0; j < 12; j++) hv[j] = h4[s*288 + j*24 + o];
    for (int i = 0; i < 12; i++){
      float v = 0.f;
      #pragma unroll
      for (int j = 0; j < 12; j++) v += p4[h*144 + i*12 + j] * hv[j];
      h4e[s*288 + i*24 + o] = elu_(v);
    }
  }
  __syncthreads();
  for (int i = t; i < 4608; i += 256) g34[s0 * 288 + i] = f2b(h4e[i]);
}

// ---------------------------------------------------------------------------
// Input projection GEMM: Xp = A[98304,144] @ Wih^T[144,576] + (bih+bhh),
// output bf16 in MFMA-frag-blocked layout [24][256][576][16].
// Grid dim3(768, 2) x 512 threads. blockIdx.y selects the 288-col half.
// ---------------------------------------------------------------------------
__global__ __launch_bounds__(512) void k_xp(
    const ushort* __restrict__ A, const float* __restrict__ Wih,
    const float* __restrict__ bih, const float* __restrict__ bhh,
    ushort* __restrict__ Xp)
{
  __shared__ ushort As[128 * 160];
  __shared__ ushort Bs[18 * 5 * 64 * 8];  // 92160 B, frag-blocked bf16
  int t = threadIdx.x;
  long row0 = (long)blockIdx.x * 128;
  int nh = blockIdx.y * 288;
  // stage A tile (K padded 144->160 with zeros)
  for (int task = t; task < 2560; task += 512){
    int row = task / 20, ch = task % 20;
    uint4 v;
    if (ch < 18) v = *(const uint4*)&A[(row0 + row) * 144 + ch * 8];
    else         v = make_uint4(0u, 0u, 0u, 0u);
    *(uint4*)&As[row * 160 + ch * 8] = v;
  }
  // stage B half in frag layout
  for (int task = t; task < 5760; task += 512){
    int l2 = task & 63, fr = task >> 6;
    int kt = fr % 5, nt = fr / 5;
    int n = nh + nt * 16 + (l2 & 15);
    int k0 = kt * 32 + (l2 >> 4) * 8;
    union { ushort u[8]; uint4 v; } pk;
    if (k0 < 144){
      const float* wp = &Wih[(long)n * 144 + k0];
      float4 a0 = *(const float4*)wp;
      float4 a1 = *(const float4*)(wp + 4);
      pk.u[0] = f2b(a0.x); pk.u[1] = f2b(a0.y); pk.u[2] = f2b(a0.z); pk.u[3] = f2b(a0.w);
      pk.u[4] = f2b(a1.x); pk.u[5] = f2b(a1.y); pk.u[6] = f2b(a1.z); pk.u[7] = f2b(a1.w);
    } else {
      pk.v = make_uint4(0u, 0u, 0u, 0u);
    }
    *(uint4*)&Bs[task * 8] = pk.v;
  }
  __syncthreads();
  int w = t >> 6, l = t & 63, q = l >> 4, ln = l & 15;
  int rblk = w * 16;
  bfrag8 af[5];
  #pragma unroll
  for (int kt = 0; kt < 5; kt++)
    af[kt] = *(const bfrag8*)&As[(rblk + ln) * 160 + kt * 32 + q * 8];
  long srow = row0 + rblk;
  int tstep = (int)(srow >> 12);
  int rb = ((int)(srow & 4095)) >> 4;
  long obase = ((long)tstep * 256 + rb) * 9216;
  for (int nt = 0; nt < 18; nt++){
    int n = nh + nt * 16 + ln;
    float b = bih[n] + bhh[n];
    ffrag4 acc = {b, b, b, b};
    #pragma unroll
    for (int kt = 0; kt < 5; kt++){
      bfrag8 bv = *(const bfrag8*)&Bs[((nt * 5 + kt) * 64 + l) * 8];
      acc = __builtin_amdgcn_mfma_f32_16x16x32_bf16(af[kt], bv, acc, 0, 0, 0);
    }
    ushort4 ov;
    ov.x = f2b(acc[0]); ov.y = f2b(acc[1]); ov.z = f2b(acc[2]); ov.w = f2b(acc[3]);
    *(ushort4*)&Xp[obase + (long)n * 16 + q * 4] = ov;
  }
}

// ---------------------------------------------------------------------------
// LSTM layer scan: 256 blocks x 576 threads (9 waves). Each block owns 16
// batch rows for all 24 steps. Whh kept in registers as B-fragments.
// Wave w owns hidden cols [16w,16w+16) of each gate -> i/f/g/o frags align.
// ---------------------------------------------------------------------------
__global__ __launch_bounds__(576) void k_scan(
    const ushort* __restrict__ Xp,   // blocked [24][256][576][16] or null
    const float* __restrict__ bih, const float* __restrict__ bhh, // if Xp==null
    const float* __restrict__ Whh,  // [576][144]
    const ushort* __restrict__ h0,  // [4096][144] bf16 or null
    ushort* __restrict__ Y,         // [98304][144] bf16 or null
    ushort* __restrict__ hT)        // [4096][144] bf16 or null
{
  __shared__ ushort hl[16 * 160];
  int t = threadIdx.x;
  int rbk = blockIdx.x;
  for (int i = t; i < 2560; i += 576) hl[i] = 0;
  __syncthreads();
  int r_cp = t / 36, ch_cp = t % 36;
  if (h0){
    *(ushort4*)&hl[r_cp * 160 + ch_cp * 4] =
        *(const ushort4*)&h0[((long)rbk * 16 + r_cp) * 144 + ch_cp * 4];
  }
  int w = t / 64, l = t & 63, q = l >> 4, ln = l & 15;
  // load Whh B-fragments (once; reused all 24 steps)
  bfrag8 bw[4][5];
  float bias[4] = {0.f, 0.f, 0.f, 0.f};
  #pragma unroll
  for (int gt = 0; gt < 4; gt++){
    int n = gt * 144 + w * 16 + ln;
    #pragma unroll
    for (int kt = 0; kt < 5; kt++){
      int k0 = kt * 32 + q * 8;
      bfrag8 bv;
      if (k0 < 144){
        const float* wp = &Whh[(long)n * 144 + k0];
        float4 a0 = *(const float4*)wp;
        float4 a1 = *(const float4*)(wp + 4);
        bv[0] = (short)f2b(a0.x); bv[1] = (short)f2b(a0.y);
        bv[2] = (short)f2b(a0.z); bv[3] = (short)f2b(a0.w);
        bv[4] = (short)f2b(a1.x); bv[5] = (short)f2b(a1.y);
        bv[6] = (short)f2b(a1.z); bv[7] = (short)f2b(a1.w);
      } else {
        bv[0]=0; bv[1]=0; bv[2]=0; bv[3]=0; bv[4]=0; bv[5]=0; bv[6]=0; bv[7]=0;
      }
      bw[gt][kt] = bv;
    }
  }
  if (!Xp){
    #pragma unroll
    for (int gt = 0; gt < 4; gt++){
      int n = gt * 144 + w * 16 + ln;
      bias[gt] = bih[n] + bhh[n];
    }
  }
  long xoff[4];
  #pragma unroll
  for (int gt = 0; gt < 4; gt++)
    xoff[gt] = ((long)(gt * 144 + w * 16 + ln)) * 16 + q * 4;
  float c[4] = {0.f, 0.f, 0.f, 0.f};
  __syncthreads();   // h0 visible, hl zero-pad visible

  ushort4 xv[4];
  if (Xp){
    long base = ((long)0 * 256 + rbk) * 9216;
    #pragma unroll
    for (int gt = 0; gt < 4; gt++) xv[gt] = *(const ushort4*)&Xp[base + xoff[gt]];
  }
  for (int ts = 0; ts < 24; ts++){
    ffrag4 acc[4];
    if (Xp){
      #pragma unroll
      for (int gt = 0; gt < 4; gt++){
        acc[gt][0] = b2f(xv[gt].x); acc[gt][1] = b2f(xv[gt].y);
        acc[gt][2] = b2f(xv[gt].z); acc[gt][3] = b2f(xv[gt].w);
      }
    } else {
      #pragma unroll
      for (int gt = 0; gt < 4; gt++){
        float b = bias[gt];
        acc[gt][0] = b; acc[gt][1] = b; acc[gt][2] = b; acc[gt][3] = b;
      }
    }
    bfrag8 af[5];
    #pragma unroll
    for (int kt = 0; kt < 5; kt++)
      af[kt] = *(const bfrag8*)&hl[ln * 160 + kt * 32 + q * 8];
    // prefetch next step's Xp during the MFMA/elementwise work
    if (Xp && ts < 23){
      long base = ((long)(ts + 1) * 256 + rbk) * 9216;
      #pragma unroll
      for (int gt = 0; gt < 4; gt++) xv[gt] = *(const ushort4*)&Xp[base + xoff[gt]];
    }
    __syncthreads();   // all h reads done before h writes
    #pragma unroll
    for (int gt = 0; gt < 4; gt++){
      #pragma unroll
      for (int kt = 0; kt < 5; kt++)
        acc[gt] = __builtin_amdgcn_mfma_f32_16x16x32_bf16(af[kt], bw[gt][kt], acc[gt], 0, 0, 0);
    }
    ushort hb[4];
    #pragma unroll
    for (int r = 0; r < 4; r++){
      float iv = acc[0][r], fv = acc[1][r], gv = acc[2][r], ov = acc[3][r];
      float cn = sigm(fv) * c[r] + sigm(iv) * tanh_(gv);
      c[r] = cn;
      hb[r] = f2b(sigm(ov) * tanh_(cn));
    }
    #pragma unroll
    for (int r = 0; r < 4; r++)
      hl[(q * 4 + r) * 160 + w * 16 + ln] = hb[r];
    __syncthreads();   // h writes visible
    if (Y){
      *(ushort4*)&Y[(((long)ts * 4096) + rbk * 16 + r_cp) * 144 + ch_cp * 4] =
          *(const ushort4*)&hl[r_cp * 160 + ch_cp * 4];
    }
  }
  if (hT){
    *(ushort4*)&hT[((long)rbk * 16 + r_cp) * 144 + ch_cp * 4] =
        *(const ushort4*)&hl[r_cp * 160 + ch_cp * 4];
  }
}

// ---------------------------------------------------------------------------
// Pre-transpose fW [288][264] into frag-blocked bf16 [17][9][64][8] (N pad 272).
// ---------------------------------------------------------------------------
__global__ void k_prep_fw(const float* __restrict__ fW, ushort* __restrict__ fWt)
{
  int bI = blockIdx.x;      // 0..152 : nt = bI/9, kt = bI%9
  int l = threadIdx.x;      // 64
  int nt = bI / 9, kt = bI % 9;
  int n = nt * 16 + (l & 15), q = l >> 4;
  for (int j = 0; j < 8; j++){
    int k = kt * 32 + q * 8 + j;
    ushort v = (n < 264) ? f2b(fW[k * 264 + n]) : (ushort)0;
    fWt[((long)bI * 64 + l) * 8 + j] = v;
  }
}

// ---------------------------------------------------------------------------
// FC [98304,288]@[288,264] + fb, leaky(0.01), fused MSE vs x -> out[98304].
// Grid 768 x 512 threads. Wave w owns ntiles {2w, 2w+1} (+16 for w==0),
// iterates all 8 row-blocks; cross-wave column reduction via LDS.
// ---------------------------------------------------------------------------
__global__ __launch_bounds__(512) void k_fc_mse(
    const ushort* __restrict__ G, const ushort* __restrict__ fWt,
    const float* __restrict__ fb, const float* __restrict__ x,
    float* __restrict__ out)
{
  __shared__ ushort As[128 * 288];
  __shared__ float psum[128 * 8];
  int t = threadIdx.x;
  long row0 = (long)blockIdx.x * 128;
  for (int i = t; i < 4608; i += 512)
    *(uint4*)&As[i * 8] = *(const uint4*)&G[row0 * 288 + i * 8];
  int w = t >> 6, l = t & 63, q = l >> 4, ln = l & 15;
  int ntl[3] = {w * 2, w * 2 + 1, 16};
  bfrag8 bw[3][9];
  float bias[3];
  #pragma unroll
  for (int ii = 0; ii < 3; ii++){
    int nt = ntl[ii];
    int n = nt * 16 + ln;
    #pragma unroll
    for (int kt = 0; kt < 9; kt++)
      bw[ii][kt] = *(const bfrag8*)&fWt[((long)(nt * 9 + kt) * 64 + l) * 8];
    bias[ii] = (n < 264) ? fb[n] : 0.f;
  }
  __syncthreads();
  for (int rb8 = 0; rb8 < 8; rb8++){
    bfrag8 af[9];
    #pragma unroll
    for (int kt = 0; kt < 9; kt++)
      af[kt] = *(const bfrag8*)&As[(rb8 * 16 + ln) * 288 + kt * 32 + q * 8];
    float s4[4] = {0.f, 0.f, 0.f, 0.f};
    #pragma unroll
    for (int ii = 0; ii < 3; ii++){
      ffrag4 acc = {bias[ii], bias[ii], bias[ii], bias[ii]};
      #pragma unroll
      for (int kt = 0; kt < 9; kt++)
        acc = __builtin_amdgcn_mfma_f32_16x16x32_bf16(af[kt], bw[ii][kt], acc, 0, 0, 0);
      int n = ntl[ii] * 16 + ln;
      bool use = (ii < 2 || w == 0) && (n < 264);
      if (use){
        #pragma unroll
        for (int r = 0; r < 4; r++){
          float v = acc[r];
          v = v > 0.f ? v : 0.01f * v;
          long row = row0 + rb8 * 16 + q * 4 + r;
          float d = x[row * 264 + n] - v;
          s4[r] += d * d;
        }
      }
    }
    #pragma unroll
    for (int off = 1; off < 16; off <<= 1){
      #pragma unroll
      for (int r = 0; r < 4; r++) s4[r] += __shfl_xor(s4[r], off, 16);
    }
    if (ln == 0){
      #pragma unroll
      for (int r = 0; r < 4; r++) psum[(rb8 * 16 + q * 4 + r) * 8 + w] = s4[r];
    }
  }
  __syncthreads();
  if (t < 128){
    float s = 0.f;
    for (int k = 0; k < 8; k++) s += psum[t * 8 + k];
    out[row0 + t] = s * (1.0f / 264.0f);
  }
}

// ---------------------------------------------------------------------------
extern "C" void kernel_launch(void* const* d_in, const int* in_sizes, int n_in,
                              void* d_out, int out_size, void* d_ws, size_t ws_size,
                              hipStream_t stream)
{
  const float* x     = (const float*)d_in[0];
  const float* gW0   = (const float*)d_in[1];
  const float* gb0   = (const float*)d_in[2];
  const float* ga0   = (const float*)d_in[3];
  const float* gW1   = (const float*)d_in[4];
  const float* gb1   = (const float*)d_in[5];
  const float* ga1   = (const float*)d_in[6];
  const float* eWih0 = (const float*)d_in[7];
  const float* eWhh0 = (const float*)d_in[8];
  const float* ebih0 = (const float*)d_in[9];
  const float* ebhh0 = (const float*)d_in[10];
  const float* eWih1 = (const float*)d_in[11];
  const float* eWhh1 = (const float*)d_in[12];
  const float* ebih1 = (const float*)d_in[13];
  const float* ebhh1 = (const float*)d_in[14];
  const float* dWih0 = (const float*)d_in[15];  (void)dWih0; // decoder L0 input is zeros
  const float* dWhh0 = (const float*)d_in[16];
  const float* dbih0 = (const float*)d_in[17];
  const float* dbhh0 = (const float*)d_in[18];
  const float* dWih1 = (const float*)d_in[19];
  const float* dWhh1 = (const float*)d_in[20];
  const float* dbih1 = (const float*)d_in[21];
  const float* dbhh1 = (const float*)d_in[22];
  const float* gW3   = (const float*)d_in[23];
  const float* gb3   = (const float*)d_in[24];
  const float* ga3   = (const float*)d_in[25];
  const float* gW4   = (const float*)d_in[26];
  const float* gb4   = (const float*)d_in[27];
  const float* ga4   = (const float*)d_in[28];
  const float* fW    = (const float*)d_in[29];
  const float* fb    = (const float*)d_in[30];

  char* ws = (char*)d_ws;
  float*  probs0 = (float*)(ws + 0);
  float*  probs1 = (float*)(ws + 2304);
  float*  probs3 = (float*)(ws + 4608);
  float*  probs4 = (float*)(ws + 6912);
  ushort* seq    = (ushort*)(ws + 9216);        // 28,311,552 B
  ushort* Ya     = (ushort*)(ws + 28320768);    // 28,311,552 B
  ushort* Yb     = (ushort*)(ws + 56632320);    // 28,311,552 B
  ushort* Xp     = (ushort*)(ws + 84943872);    // 113,246,208 B
  ushort* hT0    = (ushort*)(ws + 198190080);   // 1,179,648 B
  ushort* hT1    = (ushort*)(ws + 199369728);   // 1,179,648 B
  ushort* fWt    = (ushort*)(ws + 200549376);   // 156,672 B
  ushort* G34    = Xp;                          // alias: Xp dead before GAT34

  float* out = (float*)d_out;

  k_prep_fw<<<153, 64, 0, stream>>>(fW, fWt);
  k_probs<<<1, 576, 0, stream>>>(x, nullptr, 22,
                                 gW0, gb0, ga0, 16, 4,
                                 gW1, gb1, ga1, 12, 3,
                                 probs0, probs1);
  k_gat01<<<6144, 256, 0, stream>>>(x, gW0, gb0, gW1, gb1, probs0, probs1, seq);

  // encoder L0
  k_xp<<<dim3(768, 2), 512, 0, stream>>>(seq, eWih0, ebih0, ebhh0, Xp);
  k_scan<<<256, 576, 0, stream>>>(Xp, nullptr, nullptr, eWhh0, nullptr, Ya, hT0);
  // encoder L1 (only final h needed)
  k_xp<<<dim3(768, 2), 512, 0, stream>>>(Ya, eWih1, ebih1, ebhh1, Xp);
  k_scan<<<256, 576, 0, stream>>>(Xp, nullptr, nullptr, eWhh1, nullptr, nullptr, hT1);
  // decoder L0 (zero input -> bias only)
  k_scan<<<256, 576, 0, stream>>>(nullptr, dbih0, dbhh0, dWhh0, hT0, Yb, nullptr);
  // decoder L1
  k_xp<<<dim3(768, 2), 512, 0, stream>>>(Yb, dWih1, dbih1, dbhh1, Xp);
  k_scan<<<256, 576, 0, stream>>>(Xp, nullptr, nullptr, dWhh1, hT1, Ya, nullptr);

  k_probs<<<1, 576, 0, stream>>>(nullptr, Ya, 12,
                                 gW3, gb3, ga3, 16, 4,
                                 gW4, gb4, ga4, 24, 6,
                                 probs3, probs4);
  k_gat34<<<6144, 256, 0, stream>>>(Ya, gW3, gb3, gW4, gb4, probs3, probs4, G34);
  k_fc_mse<<<768, 512, 0, stream>>>(G34, fWt, fb, x, out);
}